// Round 3
// baseline (236.693 us; speedup 1.0000x reference)
//
#include <hip/hip_runtime.h>
#include <stdint.h>

// S4 layer, fused single-kernel, R10: occupancy recovery.
// R9b post-mortem: fused kernel 79us with MfmaUtil 2.5%, VALUBusy 27%, HBM 19%
// => latency-bound at 8 waves/CU (77KB LDS -> 2 blocks/CU of 4 waves).
// R10 restores 12 waves/CU (3/SIMD) with identical arithmetic:
//  (1) h-tile aliased into the bx-tile rows (h_j -> bxl row j; that row's u is
//      consumed >=16 rows earlier for c>0, >=1 prefetch-group for c==0) -18KB.
//  (2) 6 waves/block (384 thr): LDS = 32KB frags + 6*6.75KB tiles = 72.5KB
//      -> 2 blocks/CU -> 12 waves/CU; __launch_bounds__(384,3) caps VGPR<=170.
// Grid 342*6 = 2052 waves, 4 idle (guarded; barriers outside guards).
#define SEQ  2048
#define NBAT 32
#define DIN  256
#define DOUT 256
#define LAT  64
#define CH   32
#define WARM 16
#define WPB  6          // waves per block

typedef __attribute__((ext_vector_type(8))) short short8;  // 8 x bf16
typedef __attribute__((ext_vector_type(4))) float f32x4;

__device__ __forceinline__ float bf2f(unsigned short u) {
  return __uint_as_float(((unsigned int)u) << 16);
}
__device__ __forceinline__ unsigned short f2bf(float f) {
  unsigned int u = __float_as_uint(f);
  u += 0x7fffu + ((u >> 16) & 1u);     // RNE
  return (unsigned short)(u >> 16);
}
__device__ __forceinline__ unsigned int pack2bf(float lo, float hi) {
  unsigned int a = __float_as_uint(lo);
  unsigned int b = __float_as_uint(hi);
  a += 0x7fffu + ((a >> 16) & 1u);
  b += 0x7fffu + ((b >> 16) & 1u);
  return (a >> 16) | (b & 0xffff0000u);
}

#define PACK8(DST, VA, VB) { \
    union { unsigned int u[4]; short8 s; } _r; \
    _r.u[0] = pack2bf((VA)[0], (VA)[1]); \
    _r.u[1] = pack2bf((VA)[2], (VA)[3]); \
    _r.u[2] = pack2bf((VB)[0], (VB)[1]); \
    _r.u[3] = pack2bf((VB)[2], (VB)[3]); \
    DST = _r.s; }

// ---- bx phase: one 16-row M-tile (rows = timesteps, fixed batch b) ----
#define XDECL f32x4 x0a,x0b,x1a,x1b,x2a,x2b,x3a,x3b,x4a,x4b,x5a,x5b,x6a,x6b,x7a,x7b;
#define FXLD(K, MT) { \
    const float* _xp = X + (size_t)(base + (MT)*16 + m) * 8192 + b * 256 + (K)*32 + q*8; \
    x##K##a = *(const f32x4*)_xp;  x##K##b = *(const f32x4*)(_xp + 4); }
#define FBXK(K) { short8 _a; PACK8(_a, x##K##a, x##K##b); \
    short8 _b0 = *(const short8*)(Bl8 + ((K)*4+0)*512 + lane*8); \
    short8 _b1 = *(const short8*)(Bl8 + ((K)*4+1)*512 + lane*8); \
    short8 _b2 = *(const short8*)(Bl8 + ((K)*4+2)*512 + lane*8); \
    short8 _b3 = *(const short8*)(Bl8 + ((K)*4+3)*512 + lane*8); \
    acc0 = __builtin_amdgcn_mfma_f32_16x16x32_bf16(_a, _b0, acc0, 0, 0, 0); \
    acc1 = __builtin_amdgcn_mfma_f32_16x16x32_bf16(_a, _b1, acc1, 0, 0, 0); \
    acc2 = __builtin_amdgcn_mfma_f32_16x16x32_bf16(_a, _b2, acc2, 0, 0, 0); \
    acc3 = __builtin_amdgcn_mfma_f32_16x16x32_bf16(_a, _b3, acc3, 0, 0, 0); }
#define FTILE(MT) { \
    FXLD(0,MT) FXLD(1,MT) FXLD(2,MT) FXLD(3,MT) \
    FXLD(4,MT) FXLD(5,MT) FXLD(6,MT) FXLD(7,MT) \
    f32x4 acc0={0,0,0,0}, acc1={0,0,0,0}, acc2={0,0,0,0}, acc3={0,0,0,0}; \
    FBXK(0) FBXK(1) FBXK(2) FBXK(3) FBXK(4) FBXK(5) FBXK(6) FBXK(7) \
    _Pragma("unroll") \
    for (int r = 0; r < 4; ++r) { \
      unsigned short* _op = bxw + ((MT)*16 + q*4 + r) * 72 + m; \
      _op[ 0] = f2bf(acc0[r]);  _op[16] = f2bf(acc1[r]); \
      _op[32] = f2bf(acc2[r]);  _op[48] = f2bf(acc3[r]); } }

// ---- y phase (verified R8 pattern; hw now aliases bxw rows 0..31) ----
#define YMF(NT) { \
    short8 _f0 = *(const short8*)(Cl8 + ( 0 + NT)*512 + lane*8); \
    short8 _f1 = *(const short8*)(Cl8 + (16 + NT)*512 + lane*8); \
    C##NT = __builtin_amdgcn_mfma_f32_16x16x32_bf16(Af0, _f0, C##NT, 0, 0, 0); \
    C##NT = __builtin_amdgcn_mfma_f32_16x16x32_bf16(Af1, _f1, C##NT, 0, 0, 0); }
#define YST(NT) { \
    float* _yp = Y + ((size_t)(tb + TIL*16 + q*4) * 32 + b) * 256 + NT*16 + m; \
    _yp[0] = C##NT[0]; _yp[8192] = C##NT[1]; _yp[16384] = C##NT[2]; _yp[24576] = C##NT[3]; }
#define YTILE(TILARG) { \
    short8 Af0 = *(const short8*)(hw + (TILARG*16 + m)*72 +  0 + q*8); \
    short8 Af1 = *(const short8*)(hw + (TILARG*16 + m)*72 + 32 + q*8); \
    f32x4 C0={0,0,0,0},C1={0,0,0,0},C2={0,0,0,0},C3={0,0,0,0}, \
          C4={0,0,0,0},C5={0,0,0,0},C6={0,0,0,0},C7={0,0,0,0}, \
          C8={0,0,0,0},C9={0,0,0,0},C10={0,0,0,0},C11={0,0,0,0}, \
          C12={0,0,0,0},C13={0,0,0,0},C14={0,0,0,0},C15={0,0,0,0}; \
    YMF(0) YMF(1) YMF(2) YMF(3) YMF(4) YMF(5) YMF(6) YMF(7) \
    YMF(8) YMF(9) YMF(10) YMF(11) YMF(12) YMF(13) YMF(14) YMF(15) \
    YST(0) YST(1) YST(2) YST(3) YST(4) YST(5) YST(6) YST(7) \
    YST(8) YST(9) YST(10) YST(11) YST(12) YST(13) YST(14) YST(15) }

__global__ __launch_bounds__(384, 3) void k_fused(
    const float* __restrict__ X, const float* __restrict__ Amat,
    const float* __restrict__ Bm, const float* __restrict__ Cm,
    float* __restrict__ hout, float* __restrict__ Y) {
  __shared__ __align__(16) unsigned int BCl[8192];                // 32 KB: B frags, later C frags
  __shared__ __align__(16) unsigned short bxl[WPB * 48 * 72];     // 40.5 KB bx/h tiles (per wave)
  const int tid  = threadIdx.x;
  const int gtid = blockIdx.x * 384 + tid;
  if (gtid < 2048) hout[gtid] = 0.0f;        // h[0] = 0

#pragma unroll
  for (int ii = 0; ii < 22; ++ii) {          // stage B frags (8192 u32, 384 thr)
    const int i = ii * 384 + tid;
    if (i < 8192) {
      const int w  = i & 3, ln = (i >> 2) & 63, f = i >> 8;
      const int kc = f >> 2, nt = f & 3;
      const int row = nt * 16 + (ln & 15);
      const int col = kc * 32 + (ln >> 4) * 8 + w * 2;
      const float* p = Bm + row * 256 + col;
      BCl[i] = pack2bf(p[0], p[1]);
    }
  }
  __syncthreads();

  const int lane = tid & 63;
  const int wv   = tid >> 6;                 // 0..5
  const int wid  = blockIdx.x * WPB + wv;    // 0..2051
  const bool act = (wid < 2048);
  const int c    = wid >> 5;                 // chunk (valid when act)
  const int b    = wid & 31;
  const int m    = lane & 15, q = lane >> 4;
  const int tout = c * CH;
  int base = tout - WARM; if (base < 0) base = 0;
  unsigned short* bxw = bxl + wv * (48 * 72);
  const unsigned short* Bl8 = (const unsigned short*)BCl;

  // ---- bx phase: 48 timesteps x 64 latent for this (c,b), into LDS ----
  if (act) {
    XDECL
    FTILE(0) FTILE(1) FTILE(2)
  }
  __syncthreads();                           // all waves done reading B frags

#pragma unroll
  for (int ii = 0; ii < 22; ++ii) {          // stage C frags over B region
    const int i = ii * 384 + tid;
    if (i < 8192) {
      const int w  = i & 3, ln = (i >> 2) & 63, f = i >> 8;
      const int s  = f >> 4, nt = f & 15;
      const int row = nt * 16 + (ln & 15);
      const int col = s * 32 + (ln >> 4) * 8 + w * 2;
      const float* p = Cm + row * 64 + col;
      BCl[i] = pack2bf(p[0], p[1]);
    }
  }
  __syncthreads();                           // C ready before any wave's y phase

  if (!act) return;                          // no more barriers below

  // ---- recurrence (identical math; h outputs alias into bxw rows 0..31:
  //      row j's u is consumed >=16 rows (c>0) / >=1 group (c==0) before the
  //      h_j write, and prefetch reads run strictly ahead of writes) ----
  unsigned short* hw = bxw;                  // h tile = bxw rows 0..31
  const f32x4* Ap = (const f32x4*)(Amat + lane * 64);
  const f32x4 A0 = Ap[0],  A1 = Ap[1],  A2 = Ap[2],  A3 = Ap[3];
  const f32x4 A4 = Ap[4],  A5 = Ap[5],  A6 = Ap[6],  A7 = Ap[7];
  const f32x4 A8 = Ap[8],  A9 = Ap[9],  A10 = Ap[10], A11 = Ap[11];
  const f32x4 A12 = Ap[12], A13 = Ap[13], A14 = Ap[14], A15 = Ap[15];

  const int warmG = (tout - base) >> 2;      // 0 for c==0, else 4
  const unsigned short* up = bxw + lane;
  float c0 = bf2f(up[0]);
  float c1 = bf2f(up[72]);
  float c2 = bf2f(up[144]);
  float c3 = bf2f(up[216]);
  up += 288;

  float h = 0.0f;

#define RL(K) __uint_as_float(__builtin_amdgcn_readlane(hu, (K)))
#define G4(V, K) \
    h0 = fmaf(V[0], RL(K+0), h0); \
    h1 = fmaf(V[1], RL(K+1), h1); \
    h2 = fmaf(V[2], RL(K+2), h2); \
    h3 = fmaf(V[3], RL(K+3), h3);
#define STEP(UU) { \
    const unsigned int hu = __float_as_uint(h); \
    float h0 = (UU), h1 = 0.f, h2 = 0.f, h3 = 0.f; \
    G4(A0,  0) G4(A1,  4) G4(A2,  8) G4(A3, 12) \
    G4(A4, 16) G4(A5, 20) G4(A6, 24) G4(A7, 28) \
    G4(A8, 32) G4(A9, 36) G4(A10,40) G4(A11,44) \
    G4(A12,48) G4(A13,52) G4(A14,56) G4(A15,60) \
    h = (h0 + h1) + (h2 + h3); }

  for (int g = 0; g < warmG; ++g) {
    float n0 = bf2f(up[0]), n1 = bf2f(up[72]), n2 = bf2f(up[144]), n3 = bf2f(up[216]);
    up += 288;
    STEP(c0) STEP(c1) STEP(c2) STEP(c3)
    c0 = n0; c1 = n1; c2 = n2; c3 = n3;
  }

  float* hp = hout + (size_t)(tout + 1) * (NBAT * LAT) + b * LAT + lane;
  for (int g = 0; g < 7; ++g) {              // 7 groups with prefetch
    float n0 = bf2f(up[0]), n1 = bf2f(up[72]), n2 = bf2f(up[144]), n3 = bf2f(up[216]);
    up += 288;
    STEP(c0) hp[0]    = h;  hw[(g*4+0)*72 + lane] = f2bf(h);
    STEP(c1) hp[2048] = h;  hw[(g*4+1)*72 + lane] = f2bf(h);
    STEP(c2) hp[4096] = h;  hw[(g*4+2)*72 + lane] = f2bf(h);
    STEP(c3) hp[6144] = h;  hw[(g*4+3)*72 + lane] = f2bf(h);
    hp += 8192;
    c0 = n0; c1 = n1; c2 = n2; c3 = n3;
  }
  // last group peeled: no prefetch (avoids LDS read past the 48-row tile)
  STEP(c0) hp[0]    = h;  hw[28*72 + lane] = f2bf(h);
  STEP(c1) hp[2048] = h;  hw[29*72 + lane] = f2bf(h);
  STEP(c2) hp[4096] = h;  hw[30*72 + lane] = f2bf(h);
  STEP(c3) hp[6144] = h;  hw[31*72 + lane] = f2bf(h);
#undef STEP
#undef G4
#undef RL

  // ---- y phase: same-wave LDS RAW (lgkmcnt only, no barrier needed) ----
  const unsigned short* Cl8 = (const unsigned short*)BCl;
  const int tb = tout;
  { const int TIL = 0; YTILE(0) }
  { const int TIL = 1; YTILE(1) }
}

extern "C" void kernel_launch(void* const* d_in, const int* in_sizes, int n_in,
                              void* d_out, int out_size, void* d_ws, size_t ws_size,
                              hipStream_t stream) {
  const float* X  = (const float*)d_in[0];   // x [2048][32][256] fp32
  const float* Am = (const float*)d_in[1];   // A [64][64]
  const float* Bm = (const float*)d_in[2];   // B [64][256]
  const float* Cm = (const float*)d_in[3];   // C [256][64]

  float* Yout = (float*)d_out;                          // [2048*32*256] fp32
  float* Hout = Yout + (size_t)SEQ * NBAT * DOUT;       // [2049*32*64] fp32
  (void)d_ws; (void)ws_size;                            // d_ws unused

  k_fused<<<342, 384, 0, stream>>>(X, Am, Bm, Cm, Hout, Yout);
}

// Round 4
// 166.572 us; speedup vs baseline: 1.4210x; 1.4210x over previous
//
#include <hip/hip_runtime.h>
#include <stdint.h>

// S4 layer, R11: back to split kernels (R8-proven k_bx) + NEW MFMA-batched
// recurrence. R10 post-mortem: launch_bounds(384,3) capped VGPR at 84 ->
// ~110MB scratch spill traffic (FETCH 35->79MB, WRITE 82->147MB), kernel
// 79->138us. Occupancy theory was also wrong: all 2048 waves were already
// co-resident in R9b. Real cost: readlane-based serial recurrence
// (~132 VALU x 48 steps x 2048 waves). R11 replaces it with MFMA steps:
// wave = (chunk, 16 batches), H(64x16) <- A(64x64)@H + U via 16 MFMA/step,
// state split hi/lo bf16 (A@hi + A@lo chained fp32 acc => fp32-level
// accuracy; only A's bf16 rounding ~1e-3 is new). Layout transpose
// (D-layout -> B-frag) via per-wave LDS bounce (same-wave lgkmcnt RAW,
// R8-proven pattern). CH=16/WARM=16 -> 256 waves x 32 steps.
// k_y = R8's y-phase reading bf16 h from d_ws instead of LDS.
#define SEQ  2048
#define NBAT 32
#define LAT  64
#define CH   16
#define WARM 16

typedef __attribute__((ext_vector_type(8))) short short8;        // 8 x bf16
typedef __attribute__((ext_vector_type(4))) float f32x4;
typedef __attribute__((ext_vector_type(4))) unsigned short us4;  // 8 B
typedef __attribute__((ext_vector_type(2))) unsigned int uint2e; // 8 B

__device__ __forceinline__ float bf2f(unsigned short u) {
  return __uint_as_float(((unsigned int)u) << 16);
}
__device__ __forceinline__ unsigned short f2bf(float f) {
  unsigned int u = __float_as_uint(f);
  u += 0x7fffu + ((u >> 16) & 1u);     // RNE
  return (unsigned short)(u >> 16);
}
__device__ __forceinline__ unsigned int pack2bf(float lo, float hi) {
  unsigned int a = __float_as_uint(lo);
  unsigned int b = __float_as_uint(hi);
  a += 0x7fffu + ((a >> 16) & 1u);
  b += 0x7fffu + ((b >> 16) & 1u);
  return (a >> 16) | (b & 0xffff0000u);
}

#define PACK8(DST, VA, VB) { \
    union { unsigned int u[4]; short8 s; } _r; \
    _r.u[0] = pack2bf((VA)[0], (VA)[1]); \
    _r.u[1] = pack2bf((VA)[2], (VA)[3]); \
    _r.u[2] = pack2bf((VB)[0], (VB)[1]); \
    _r.u[3] = pack2bf((VB)[2], (VB)[3]); \
    DST = _r.s; }

// ---------------- K1: bx = X @ B^T (verbatim R8, proven) ----------------
#define XDECL(P) f32x4 P##0a,P##0b,P##1a,P##1b,P##2a,P##2b,P##3a,P##3b, \
                       P##4a,P##4b,P##5a,P##5b,P##6a,P##6b,P##7a,P##7b;
#define XLD(P,K,R) { const float* _xp = X + (size_t)((R) + m) * 256 + (K)*32 + q*8; \
    P##K##a = *(const f32x4*)_xp;  P##K##b = *(const f32x4*)(_xp + 4); }
#define XLDALL(P,R) XLD(P,0,R) XLD(P,1,R) XLD(P,2,R) XLD(P,3,R) \
                    XLD(P,4,R) XLD(P,5,R) XLD(P,6,R) XLD(P,7,R)
#define BXK(P,K) { short8 _a; PACK8(_a, P##K##a, P##K##b); \
    short8 _b0 = *(const short8*)(Bl8 + ((K)*4+0)*512 + lane*8); \
    short8 _b1 = *(const short8*)(Bl8 + ((K)*4+1)*512 + lane*8); \
    short8 _b2 = *(const short8*)(Bl8 + ((K)*4+2)*512 + lane*8); \
    short8 _b3 = *(const short8*)(Bl8 + ((K)*4+3)*512 + lane*8); \
    acc0 = __builtin_amdgcn_mfma_f32_16x16x32_bf16(_a, _b0, acc0, 0, 0, 0); \
    acc1 = __builtin_amdgcn_mfma_f32_16x16x32_bf16(_a, _b1, acc1, 0, 0, 0); \
    acc2 = __builtin_amdgcn_mfma_f32_16x16x32_bf16(_a, _b2, acc2, 0, 0, 0); \
    acc3 = __builtin_amdgcn_mfma_f32_16x16x32_bf16(_a, _b3, acc3, 0, 0, 0); }
#define BXTILE(P,R) { \
    f32x4 acc0={0,0,0,0}, acc1={0,0,0,0}, acc2={0,0,0,0}, acc3={0,0,0,0}; \
    BXK(P,0) BXK(P,1) BXK(P,2) BXK(P,3) BXK(P,4) BXK(P,5) BXK(P,6) BXK(P,7) \
    _Pragma("unroll") \
    for (int r = 0; r < 4; ++r) { \
      unsigned short* _op = bxh + (size_t)((R) + q*4 + r) * 64 + m; \
      _op[ 0] = f2bf(acc0[r]);  _op[16] = f2bf(acc1[r]); \
      _op[32] = f2bf(acc2[r]);  _op[48] = f2bf(acc3[r]); } }

__global__ __launch_bounds__(256) void k_bx(const float* __restrict__ X,
                                            const float* __restrict__ Bm,
                                            unsigned short* __restrict__ bxh,
                                            float* __restrict__ hout) {
  __shared__ unsigned int Bl[8192];          // 32 KB: frag(kc*4+nt) x lane x w
  const int tid = threadIdx.x;
  if (blockIdx.x < 8) hout[blockIdx.x * 256 + tid] = 0.0f;   // h[0] = 0

#pragma unroll
  for (int ii = 0; ii < 32; ++ii) {          // stage B: 8192 u32, one-time
    const int i  = ii * 256 + tid;
    const int w  = i & 3, ln = (i >> 2) & 63, f = i >> 8;
    const int kc = f >> 2, nt = f & 3;
    const int row = nt * 16 + (ln & 15);
    const int col = kc * 32 + (ln >> 4) * 8 + w * 2;
    const float* p = Bm + row * 256 + col;
    Bl[i] = pack2bf(p[0], p[1]);
  }
  __syncthreads();

  const int lane = tid & 63;
  const int m = lane & 15, q = lane >> 4;
  const unsigned short* Bl8 = (const unsigned short*)Bl;
  const int wid = blockIdx.x * 4 + (tid >> 6);   // 0..2047
  const int R0  = wid * 32;

  XDECL(Xa) XDECL(Xb)
  XLDALL(Xa, R0)
  XLDALL(Xb, R0 + 16)
  BXTILE(Xa, R0)
  BXTILE(Xb, R0 + 16)
}

// -------- K2: MFMA-batched recurrence --------
// Wave = (chunk c, batch-half g): H state = 64 latent x 16 batches.
// Step: D_mi = U_mi; D += A(mi,kb)@Hhi(kb) + A(mi,kb)@Hlo(kb)  (4 chained
// MFMA per tile, fp32 acc). D-layout lane(q,m): rows 16mi+4q+r, batch col m.
// Next step's B-frag (lane(q,m) needs H[32kb+8q+j][m]) comes from lanes
// s0=32(q&1)+m and s1=s0+16, tile mi=2kb+(q>>1), reg pairs (0,1),(2,3)
// -> per-wave LDS bounce: each lane writes its 8 hi + 8 lo packed u32,
// reads 4x8B per frag. Same-wave cross-lane LDS RAW (lgkmcnt, no barrier)
// is the R8-proven hw-tile pattern.
#define MSTEP(AF0, AF1, DD) \
    DD = __builtin_amdgcn_mfma_f32_16x16x32_bf16(AF0, Bhi0, DD, 0, 0, 0); \
    DD = __builtin_amdgcn_mfma_f32_16x16x32_bf16(AF1, Bhi1, DD, 0, 0, 0); \
    DD = __builtin_amdgcn_mfma_f32_16x16x32_bf16(AF0, Blo0, DD, 0, 0, 0); \
    DD = __builtin_amdgcn_mfma_f32_16x16x32_bf16(AF1, Blo1, DD, 0, 0, 0);

// hi = RNE bf16 (matches old f2bf exactly -> y-path numerics preserved);
// lo = exact fp32 residual, trunc-packed (residual of residual ~2^-17).
#define SPLIT(MI, DD) \
    const unsigned int hh##MI##_0 = pack2bf(DD[0], DD[1]); \
    const unsigned int hh##MI##_1 = pack2bf(DD[2], DD[3]); \
    { float _f0 = __uint_as_float(hh##MI##_0 << 16); \
      float _f1 = __uint_as_float(hh##MI##_0 & 0xffff0000u); \
      float _f2 = __uint_as_float(hh##MI##_1 << 16); \
      float _f3 = __uint_as_float(hh##MI##_1 & 0xffff0000u); \
      unsigned int _l01 = (__float_as_uint(DD[0] - _f0) >> 16) | \
                          (__float_as_uint(DD[1] - _f1) & 0xffff0000u); \
      unsigned int _l23 = (__float_as_uint(DD[2] - _f2) >> 16) | \
                          (__float_as_uint(DD[3] - _f3) & 0xffff0000u); \
      wptr[2*(MI)]     = hh##MI##_0;  wptr[2*(MI)+1]   = hh##MI##_1; \
      wptr[8+2*(MI)]   = _l01;        wptr[8+2*(MI)+1] = _l23; }

#define RDB(KB, BH, BL) { \
    const unsigned int* _r0 = &bounce[32*(q&1) + m][2*(2*(KB) + (q>>1))]; \
    const unsigned int* _r1 = _r0 + 16*18; \
    union { unsigned int u[4]; short8 s; } _h, _l; \
    *(uint2e*)&_h.u[0] = *(const uint2e*)_r0; \
    *(uint2e*)&_h.u[2] = *(const uint2e*)_r1; \
    *(uint2e*)&_l.u[0] = *(const uint2e*)(_r0 + 8); \
    *(uint2e*)&_l.u[2] = *(const uint2e*)(_r1 + 8); \
    BH = _h.s; BL = _l.s; }

#define RSTEP(T, STORE) { \
    us4 un0, un1, un2, un3; \
    { const unsigned short* _p = ub + (size_t)((T) + 1) * 2048; \
      un0 = *(const us4*)(_p);      un1 = *(const us4*)(_p + 16); \
      un2 = *(const us4*)(_p + 32); un3 = *(const us4*)(_p + 48); } \
    f32x4 D0 = {bf2f(uc0[0]), bf2f(uc0[1]), bf2f(uc0[2]), bf2f(uc0[3])}; \
    f32x4 D1 = {bf2f(uc1[0]), bf2f(uc1[1]), bf2f(uc1[2]), bf2f(uc1[3])}; \
    f32x4 D2 = {bf2f(uc2[0]), bf2f(uc2[1]), bf2f(uc2[2]), bf2f(uc2[3])}; \
    f32x4 D3 = {bf2f(uc3[0]), bf2f(uc3[1]), bf2f(uc3[2]), bf2f(uc3[3])}; \
    MSTEP(Af00, Af01, D0) MSTEP(Af10, Af11, D1) \
    MSTEP(Af20, Af21, D2) MSTEP(Af30, Af31, D3) \
    if (STORE) { \
      float* _hp = hout + ((size_t)(T) + 1) * 2048 + b * 64 + 4 * q; \
      *(f32x4*)(_hp)      = D0;  *(f32x4*)(_hp + 16) = D1; \
      *(f32x4*)(_hp + 32) = D2;  *(f32x4*)(_hp + 48) = D3; } \
    SPLIT(0, D0) SPLIT(1, D1) SPLIT(2, D2) SPLIT(3, D3) \
    if (STORE) { \
      unsigned int* _hb = (unsigned int*)(hbf + (size_t)(T) * 2048 + b * 64 + 4 * q); \
      _hb[0]  = hh0_0; _hb[1]  = hh0_1;  _hb[8]  = hh1_0; _hb[9]  = hh1_1; \
      _hb[16] = hh2_0; _hb[17] = hh2_1;  _hb[24] = hh3_0; _hb[25] = hh3_1; } \
    RDB(0, Bhi0, Blo0) RDB(1, Bhi1, Blo1) \
    uc0 = un0; uc1 = un1; uc2 = un2; uc3 = un3; }

__global__ __launch_bounds__(64) void k_rec(const float* __restrict__ Amat,
                                            const unsigned short* __restrict__ bxh,
                                            float* __restrict__ hout,
                                            unsigned short* __restrict__ hbf) {
  __shared__ unsigned int bounce[64][18];    // 4.6 KB, per-wave bounce (pad 18)
  const int lane = threadIdx.x;              // one wave per block
  const int wid  = blockIdx.x;               // 0..255
  const int c    = wid >> 1;                 // chunk 0..127
  const int g    = wid & 1;                  // batch half
  const int q    = lane >> 4, m = lane & 15;
  const int b    = g * 16 + m;
  unsigned int* wptr = &bounce[lane][0];

  // A frags (bf16 RNE): Af(mi,kb) lane(q,m) = A[16mi+m][32kb+8q+j], j=0..7
  short8 Af00, Af01, Af10, Af11, Af20, Af21, Af30, Af31;
#define LDA(MI, KB, DST) { \
    const float* _ap = Amat + (16*(MI) + m) * 64 + 32*(KB) + 8*q; \
    f32x4 _a = *(const f32x4*)_ap; f32x4 _c = *(const f32x4*)(_ap + 4); \
    PACK8(DST, _a, _c); }
  LDA(0,0,Af00) LDA(0,1,Af01) LDA(1,0,Af10) LDA(1,1,Af11)
  LDA(2,0,Af20) LDA(2,1,Af21) LDA(3,0,Af30) LDA(3,1,Af31)
#undef LDA

  short8 Bhi0 = {0,0,0,0,0,0,0,0}, Bhi1 = {0,0,0,0,0,0,0,0};
  short8 Blo0 = {0,0,0,0,0,0,0,0}, Blo1 = {0,0,0,0,0,0,0,0};

  const int tout = c * CH;
  int t0 = tout - WARM; if (t0 < 0) t0 = 0;
  const unsigned short* ub = bxh + (size_t)b * LAT + 4 * q;  // +t*2048, +16*mi

  us4 uc0, uc1, uc2, uc3;
  { const unsigned short* _p = ub + (size_t)t0 * 2048;
    uc0 = *(const us4*)(_p);      uc1 = *(const us4*)(_p + 16);
    uc2 = *(const us4*)(_p + 32); uc3 = *(const us4*)(_p + 48); }

  for (int t = t0; t < tout; ++t) { RSTEP(t, 0) }     // warm (no stores)
  for (int t = tout; t < tout + CH; ++t) { RSTEP(t, 1) }
  // note: last prefetch reads t=tout+CH (c=127 -> t=2048, lands harmlessly
  // in the hbf region of d_ws; value never used)
}

// -------- K3: y = h_bf16 @ C^T (R8 y-phase, A-frags from global) --------
#define YMF(NT) { \
    short8 _f0 = *(const short8*)(Cl8 + ( 0 + NT)*512 + lane*8); \
    short8 _f1 = *(const short8*)(Cl8 + (16 + NT)*512 + lane*8); \
    C##NT = __builtin_amdgcn_mfma_f32_16x16x32_bf16(Af0, _f0, C##NT, 0, 0, 0); \
    C##NT = __builtin_amdgcn_mfma_f32_16x16x32_bf16(Af1, _f1, C##NT, 0, 0, 0); }
#define YST(NT) { \
    float* _yp = Y + (size_t)(R0 + TIL*16 + q*4) * 256 + NT*16 + m; \
    _yp[0] = C##NT[0]; _yp[256] = C##NT[1]; _yp[512] = C##NT[2]; _yp[768] = C##NT[3]; }
#define YTILE(TILARG) { \
    const int TIL = (TILARG); \
    const unsigned short* _hr = hbf + (size_t)(R0 + TIL*16 + m) * 64; \
    short8 Af0 = *(const short8*)(_hr + q*8); \
    short8 Af1 = *(const short8*)(_hr + 32 + q*8); \
    f32x4 C0={0,0,0,0},C1={0,0,0,0},C2={0,0,0,0},C3={0,0,0,0}, \
          C4={0,0,0,0},C5={0,0,0,0},C6={0,0,0,0},C7={0,0,0,0}, \
          C8={0,0,0,0},C9={0,0,0,0},C10={0,0,0,0},C11={0,0,0,0}, \
          C12={0,0,0,0},C13={0,0,0,0},C14={0,0,0,0},C15={0,0,0,0}; \
    YMF(0) YMF(1) YMF(2) YMF(3) YMF(4) YMF(5) YMF(6) YMF(7) \
    YMF(8) YMF(9) YMF(10) YMF(11) YMF(12) YMF(13) YMF(14) YMF(15) \
    YST(0) YST(1) YST(2) YST(3) YST(4) YST(5) YST(6) YST(7) \
    YST(8) YST(9) YST(10) YST(11) YST(12) YST(13) YST(14) YST(15) }

__global__ __launch_bounds__(256) void k_y(const unsigned short* __restrict__ hbf,
                                           const float* __restrict__ Cm,
                                           float* __restrict__ Y) {
  __shared__ unsigned int Cl[8192];          // 32 KB C frags
  const int tid = threadIdx.x;

#pragma unroll
  for (int ii = 0; ii < 32; ++ii) {          // stage C in frag order (R8)
    const int i  = ii * 256 + tid;
    const int w  = i & 3, ln = (i >> 2) & 63, f = i >> 8;
    const int s  = f >> 4, nt = f & 15;
    const int row = nt * 16 + (ln & 15);
    const int col = s * 32 + (ln >> 4) * 8 + w * 2;
    const float* p = Cm + row * 64 + col;
    Cl[i] = pack2bf(p[0], p[1]);
  }
  __syncthreads();

  const int lane = tid & 63;
  const int m = lane & 15, q = lane >> 4;
  const unsigned short* Cl8 = (const unsigned short*)Cl;
  const int wid = blockIdx.x * 4 + (tid >> 6);   // 0..2047
  const int R0  = wid * 32;                      // flat rows t*32+b

  YTILE(0)
  YTILE(1)
}

extern "C" void kernel_launch(void* const* d_in, const int* in_sizes, int n_in,
                              void* d_out, int out_size, void* d_ws, size_t ws_size,
                              hipStream_t stream) {
  const float* X  = (const float*)d_in[0];   // x [2048][32][256] fp32
  const float* Am = (const float*)d_in[1];   // A [64][64]
  const float* Bm = (const float*)d_in[2];   // B [64][256]
  const float* Cm = (const float*)d_in[3];   // C [256][64]

  float* Yout = (float*)d_out;                          // [2048*32*256] fp32
  float* Hout = Yout + (size_t)SEQ * NBAT * 256;        // [2049*32*64] fp32
  unsigned short* bxh = (unsigned short*)d_ws;                       // 8.4 MB
  unsigned short* hbf = bxh + (size_t)SEQ * NBAT * LAT;              // 8.4 MB

  k_bx <<<512, 256, 0, stream>>>(X, Bm, bxh, Hout);
  k_rec<<<256,  64, 0, stream>>>(Am, bxh, Hout, hbf);
  k_y  <<<512, 256, 0, stream>>>(hbf, Cm, Yout);
}